// Round 14
// baseline (68.339 us; speedup 1.0000x reference)
//
#include <hip/hip_runtime.h>
#include <math.h>

// Problem constants: gts/preds [4, 8192, 3] fp32; out [4] fp32.
#define BB 4
#define NPTS 8192
#define THREADS 512                    // 8 waves/block
#define NQ_TOTAL (2 * BB * NPTS)       // 65536 (dir,b,point) query slots
#define QBLK 512                       // queries per block (8 waves x 64)
#define QPWV 64                        // queries per wave (2 B-frags)
#define QUARTN 2048                    // refs per block (4-way ref split)
#define NFRAG (QUARTN / 32)            // 64 A-frags
#define FBLK 512                       // 4 quarters x 2 dir x 4 b x 16 qgroups

typedef __attribute__((ext_vector_type(4)))  short bf16x4;   // K=8 MFMA A/B frag
typedef __attribute__((ext_vector_type(16))) float f32x16;   // MFMA C/D frag

// ws layout:
//   minpart: float[4][NQ_TOTAL] per-quarter partial d^2 mins        1 MiB
//
// R29 = R24 VERBATIM (the best passing kernel, 68.2us).  Post-mortem of
// the failed experiments beyond it:
//  - R25 cooperative grid.sync: launch fails under harness graph capture.
//  - R26/R27 single-kernel fence/atomic merge fusion: stale cross-XCD
//    reads both times -- kernel boundary is the only reliable visibility
//    mechanism here (G16 in practice).
//  - R28 inline-asm v_min3 on MFMA results: MISCOMPILE -- LLVM's hazard
//    recognizer does not insert MFMA->VALU wait-states for an opaque
//    inline-asm consumer; the asm read the MFMA dest before it was
//    written.  Never feed MFMA results directly into inline asm.  (The
//    fminf(fminf(a,b),c) pattern below already fuses to v_min3 natively.)
//  - R19-R23: ILP depth / LDS traffic / waves-per-SIMD / K=8-vs-K=16 all
//    within +-1us -- chamfer's MFMA+VALU pipes are jointly ~saturated
//    (R22 diagnostic: MfmaUtil 52%, VALUBusy 60%).
// Structure: fused pack+chamfer (512 blocks = 2/CU, 4 waves/SIMD, K=8
// lo/hi planes, depth-4 A-ring, immediate fold) -> plain-store quarter min
// slices -> separate merge kernel (min of 4 slices, sqrt, block-reduce,
// atomicAdd into out[b]).

__device__ __forceinline__ unsigned short f2bf(float f) {   // RNE f32->bf16
    unsigned u = __float_as_uint(f);
    u += 0x7FFF + ((u >> 16) & 1);
    return (unsigned short)(u >> 16);
}
__device__ __forceinline__ float bf2f(unsigned short h) {
    return __uint_as_float(((unsigned)h) << 16);
}

#define ONE16 ((unsigned short)0x3F80)      // 1.0 bf16

// Pack one ref point (fp32 x,y,z) into lo/hi uint2 planes:
// lo = [x, y | z, rr_hi], hi = [rr_lo, 1 | 1, 0].
#define PACKR(X, Y, Z, LO, HI)                                              \
    {                                                                       \
        unsigned short hx = f2bf(X), hy = f2bf(Y), hz = f2bf(Z);            \
        float fx = bf2f(hx), fy = bf2f(hy), fz = bf2f(hz);                  \
        float rr = fmaf(fx, fx, fmaf(fy, fy, fz * fz));                     \
        unsigned short hrr = f2bf(rr), hlo = f2bf(rr - bf2f(hrr));          \
        (LO).x = (unsigned)hx  | ((unsigned)hy  << 16);                     \
        (LO).y = (unsigned)hz  | ((unsigned)hrr << 16);                     \
        (HI).x = (unsigned)hlo | ((unsigned)ONE16 << 16);                   \
        (HI).y = (unsigned)ONE16;                                           \
    }

// Build this lane's K-half of a query B-frag from fp32 x,y,z:
// khalf0 = [-2x,-2y,-2z,1], khalf1 = [1,qq_hi,qq_lo,0].
#define PACKQ(X, Y, Z, BQ)                                                  \
    {                                                                       \
        unsigned short hx = f2bf(X), hy = f2bf(Y), hz = f2bf(Z);            \
        float fx = bf2f(hx), fy = bf2f(hy), fz = bf2f(hz);                  \
        float qq = fmaf(fx, fx, fmaf(fy, fy, fz * fz));                     \
        unsigned short hq = f2bf(qq), hql = f2bf(qq - bf2f(hq));            \
        if (khalf == 0) {                                                   \
            (BQ)[0] = (short)f2bf(-2.0f * fx);                              \
            (BQ)[1] = (short)f2bf(-2.0f * fy);                              \
            (BQ)[2] = (short)f2bf(-2.0f * fz);                              \
            (BQ)[3] = (short)ONE16;                                         \
        } else {                                                            \
            (BQ)[0] = (short)ONE16;                                         \
            (BQ)[1] = (short)hq;                                            \
            (BQ)[2] = (short)hql;                                           \
            (BQ)[3] = 0;                                                    \
        }                                                                   \
    }

// Fold one D frag into 4 independent running-min chains.
// fminf(fminf(a,b),c) fuses to v_min3_f32 natively (no inline asm!).
#define FOLD8(P, X0, X1, X2, X3)                                   \
    X0 = fminf(fminf((P)[0],  (P)[1]),  X0);                       \
    X1 = fminf(fminf((P)[2],  (P)[3]),  X1);                       \
    X2 = fminf(fminf((P)[4],  (P)[5]),  X2);                       \
    X3 = fminf(fminf((P)[6],  (P)[7]),  X3);                       \
    X0 = fminf(fminf((P)[8],  (P)[9]),  X0);                       \
    X1 = fminf(fminf((P)[10], (P)[11]), X1);                       \
    X2 = fminf(fminf((P)[12], (P)[13]), X2);                       \
    X3 = fminf(fminf((P)[14], (P)[15]), X3);

#define MFMA8(A, B, C) __builtin_amdgcn_mfma_f32_32x32x8bf16_1k(A, B, C, 0, 0, 0)

// One step: 2 K=8 MFMAs consume ring slot AQ (frag F), refill AQ with frag
// F+4 if it exists, fold both D-frags immediately (per-wave result-latency
// stalls are covered by the 3 sibling waves on this SIMD).
#define STEP(AQ, FN, DO_LOAD)                                               \
    {                                                                       \
        f32x16 d0 = MFMA8(AQ, bq0, zc);                                     \
        f32x16 d1 = MFMA8(AQ, bq1, zc);                                     \
        if (DO_LOAD) AQ = spv[poff + (FN) * 32 + l31];                      \
        FOLD8(d0, c0, c1, c2, c3);                                          \
        FOLD8(d1, c4, c5, c6, c7);                                          \
    }

// ---------------------------------------------------------------------------
// Kernel 1 (fused pack + chamfer): per block = one (quarter, dir, b,
// 512-query group), 8 waves, 2 blocks/CU (grid 512, 32KB LDS) = 4 waves/
// SIMD.  Block packs its 2048-ref quarter from raw fp32 into LDS bf16
// planes; each lane builds 2 query B-frags from raw fp32.  Main loop: each
// A-frag ds_read_b64 feeds 2 K=8 MFMAs.  Epilogue: clamp >= 0, plain-store
// partial mins into this quarter's minpart slice.
// D layout (m74/m101): col = lane&31, row = (r&3)+8*(r>>2)+4*(lane>>5).
// ---------------------------------------------------------------------------
__global__ __launch_bounds__(THREADS, 4) void chamfer_kernel(
    const float* __restrict__ gts, const float* __restrict__ preds,
    float* __restrict__ minpart, float* __restrict__ out) {
    __shared__ uint2 sref[2][QUARTN];      // 32 KB: [0]=lo plane, [1]=hi

    int tid  = threadIdx.x;
    int blk  = blockIdx.x;                 // [0, 512)
    int quart= blk >> 7;                   // ref quarter 0..3
    int dir  = (blk >> 6) & 1;             // 0: q=preds r=gts; 1: q=gts r=preds
    int b    = (blk >> 4) & 3;
    int qg   = blk & 15;                   // query group of 512
    int wid  = tid >> 6;                   // 0..7
    int lane = tid & 63;
    int l31  = lane & 31;
    int khalf= lane >> 5;                  // 0 = K slots 0-3, 1 = K slots 4-7

    if (blk == 0 && tid < BB) out[tid] = 0.0f;   // stream-ordered vs merge

    // ---- Query B-frags from raw fp32 (L2-hot, 384B window per wave-half).
    const float* qsrc = (dir ^ 1) ? preds : gts;
    size_t qpt = (size_t)b * NPTS + (size_t)qg * QBLK + (size_t)wid * QPWV + l31;
    float qx0 = qsrc[qpt * 3],        qy0 = qsrc[qpt * 3 + 1],
          qz0 = qsrc[qpt * 3 + 2];
    float qx1 = qsrc[(qpt + 32) * 3], qy1 = qsrc[(qpt + 32) * 3 + 1],
          qz1 = qsrc[(qpt + 32) * 3 + 2];
    bf16x4 bq0, bq1;
    PACKQ(qx0, qy0, qz0, bq0);
    PACKQ(qx1, qy1, qz1, bq1);

    // ---- Pack this block's 2048-ref quarter into LDS planes.
    // Thread t packs points 4t..4t+3 (3 float4 loads, L2-hot).
    const float* rsrc = dir ? preds : gts;
    size_t rfbase = ((size_t)b * NPTS + (size_t)quart * QUARTN) * 3;
    const float4* rf4 = (const float4*)(rsrc + rfbase);
    float4 f0 = rf4[3 * tid], f1 = rf4[3 * tid + 1], f2 = rf4[3 * tid + 2];
    uint2 l0, l1, l2, l3, h0, h1, h2, h3;
    PACKR(f0.x, f0.y, f0.z, l0, h0);
    PACKR(f0.w, f1.x, f1.y, l1, h1);
    PACKR(f1.z, f1.w, f2.x, l2, h2);
    PACKR(f2.y, f2.z, f2.w, l3, h3);
    uint4* dlo = (uint4*)&sref[0][4 * tid];
    dlo[0] = make_uint4(l0.x, l0.y, l1.x, l1.y);
    dlo[1] = make_uint4(l2.x, l2.y, l3.x, l3.y);
    uint4* dhi = (uint4*)&sref[1][4 * tid];
    dhi[0] = make_uint4(h0.x, h0.y, h1.x, h1.y);
    dhi[1] = make_uint4(h2.x, h2.y, h3.x, h3.y);
    __syncthreads();                       // planes ready

    f32x16 zc;
    #pragma unroll
    for (int r = 0; r < 16; ++r) zc[r] = 0.0f;

    float c0 = 3.0e38f, c1 = 3.0e38f, c2 = 3.0e38f, c3 = 3.0e38f;
    float c4 = 3.0e38f, c5 = 3.0e38f, c6 = 3.0e38f, c7 = 3.0e38f;

    const bf16x4* spv = (const bf16x4*)sref;
    const int poff = khalf * QUARTN;       // this lane's plane in LDS

    // Depth-4 prefetch ring (frags 0-3).
    bf16x4 a0 = spv[poff + 0 * 32 + l31];
    bf16x4 a1 = spv[poff + 1 * 32 + l31];
    bf16x4 a2 = spv[poff + 2 * 32 + l31];
    bf16x4 a3 = spv[poff + 3 * 32 + l31];

    // 16 macro-steps x 4 frags; ds offsets compile-time after unroll.
    #pragma unroll
    for (int m = 0; m < NFRAG / 4; ++m) {
        const bool L = (m < NFRAG / 4 - 1);          // last quartet: no refill
        STEP(a0, (m + 1) * 4 + 0, L);
        STEP(a1, (m + 1) * 4 + 1, L);
        STEP(a2, (m + 1) * 4 + 2, L);
        STEP(a3, (m + 1) * 4 + 3, L);
    }

    // Per-query partial min: lane halves hold complementary ref-rows.
    float m0 = fminf(fminf(c0, c1), fminf(c2, c3));
    m0 = fminf(m0, __shfl_xor(m0, 32, 64));
    float m1 = fminf(fminf(c4, c5), fminf(c6, c7));
    m1 = fminf(m1, __shfl_xor(m1, 32, 64));

    // Plain-store this quarter's partial mins (clamped >= 0): no atomics.
    size_t qid = (size_t)(dir * BB + b) * NPTS + (size_t)qg * QBLK
               + (size_t)wid * QPWV;
    float* mp = minpart + (size_t)quart * NQ_TOTAL + qid;
    if (lane < 32) {
        mp[l31]      = fmaxf(m0, 0.0f);
        mp[32 + l31] = fmaxf(m1, 0.0f);
    }
}

// ---------------------------------------------------------------------------
// Kernel 2: merge — min across the 4 quarter slices, sqrt, sum, atomicAdd.
// 64 blocks x 256 thr, 4 queries per thread (float4 per slice).
// ---------------------------------------------------------------------------
__global__ __launch_bounds__(256) void merge_kernel(
    const float* __restrict__ minpart, float* __restrict__ out) {
    int t = blockIdx.x * 256 + threadIdx.x;        // float4 index [0,16384)
    const float4* mp4 = (const float4*)minpart;
    float4 v0 = mp4[t];
    float4 v1 = mp4[t + NQ_TOTAL / 4];
    float4 v2 = mp4[t + 2 * (NQ_TOTAL / 4)];
    float4 v3 = mp4[t + 3 * (NQ_TOTAL / 4)];
    float mx = fminf(fminf(v0.x, v1.x), fminf(v2.x, v3.x));
    float my = fminf(fminf(v0.y, v1.y), fminf(v2.y, v3.y));
    float mz = fminf(fminf(v0.z, v1.z), fminf(v2.z, v3.z));
    float mw = fminf(fminf(v0.w, v1.w), fminf(v2.w, v3.w));
    float d = sqrtf(mx) + sqrtf(my) + sqrtf(mz) + sqrtf(mw);
    int b = (t >> 11) & 3;                         // uniform within a block

    #pragma unroll
    for (int off = 32; off > 0; off >>= 1)
        d += __shfl_down(d, off, 64);

    __shared__ float wsum[4];
    int lane = threadIdx.x & 63;
    int wid  = threadIdx.x >> 6;
    if (lane == 0) wsum[wid] = d;
    __syncthreads();
    if (threadIdx.x == 0)
        atomicAdd(out + b, wsum[0] + wsum[1] + wsum[2] + wsum[3]);
}

extern "C" void kernel_launch(void* const* d_in, const int* in_sizes, int n_in,
                              void* d_out, int out_size, void* d_ws, size_t ws_size,
                              hipStream_t stream) {
    const float* gts   = (const float*)d_in[0];
    const float* preds = (const float*)d_in[1];
    float* out = (float*)d_out;

    float* minpart = (float*)d_ws;                 // 4 x 256 KiB slices

    chamfer_kernel<<<FBLK, THREADS, 0, stream>>>(gts, preds, minpart, out);

    merge_kernel<<<NQ_TOTAL / 4 / 256, 256, 0, stream>>>(minpart, out);
}